// Round 12
// baseline (43.359 us; speedup 1.0000x reference)
//
#include <hip/hip_runtime.h>

// Local windowed 2D autocorrelation.
// x: [8, 64, 128, 128] fp32; out: [8, 64, 31, 31, 8, 8] fp32.
// KH=KW=8, SH=SW=4, no padding.
//
// Round 12 = round 10 compute + FAT BLOCKS (1024 thr = 16 waves = 4
// independent tile-groups, one barrier, no serial tile loop).
// Evidence chain: block lifetime ~2.6us vs ~0.5us serial work at ~1.4
// resident blocks/CU (round 6); persistent loops regressed because they
// SERIALIZED tiles (rounds 8/9); prefetch null (round 11). One CP dispatch
// now delivers 16 waves; 4 tiles/block are adjacent hp of one bc-plane ->
// block output is ONE contiguous 63.5KB run, streamed by all 1024 threads.
// Task rebalance to 4 waves/tile: {D4+D0}, {D1}, {D2}, {D3} (~200-230
// packed slots each).
//
// Carried lessons: packed fp32 FMA (round 10: 61->42us); LDS assembly +
// coalesced full-line copy-out (round 5: scattered 32B stores = 3.75x write
// amp); XOR-swizzle by (w&7) = conflict-free; launch_bounds cap >= live set
// (round 2: forcing below live set = catastrophic spill).

#define NH 31
#define NW 31

typedef float f32x4 __attribute__((ext_vector_type(4)));
typedef float f32x2 __attribute__((ext_vector_type(2)));

__device__ __forceinline__ void loadrow(const float* p, float r[8]) {
  f32x4 a = *reinterpret_cast<const f32x4*>(p);
  f32x4 b = *reinterpret_cast<const f32x4*>(p + 4);
  r[0] = a.x; r[1] = a.y; r[2] = a.z; r[3] = a.w;
  r[4] = b.x; r[5] = b.y; r[6] = b.z; r[7] = b.w;
}

// Task for dy = -D (output rows oy=4-D and mirror 4+D), D in 1..4.
// acc2[p] = {acc[2p], acc[2p+1]}, acc[ox] = sum_{i>=D, j} W[i][j]*W[i-D][j+ox-4].
// e (if WE) = mirror-row edge value (ox=0 of row 4+D).
template <int D, bool WE>
__device__ __forceinline__ void corr_task_pk(const float* src, f32x2 acc2[4], float& e) {
  float R[8][8];
#pragma unroll
  for (int i = 0; i < 8; ++i) loadrow(src + i * 128, R[i]);

  f32x2 e2 = {0.f, 0.f};
#pragma unroll
  for (int i = D; i < 8; ++i) {
    const float(&ra)[8] = R[i];
    const float(&rb)[8] = R[i - D];
#pragma unroll
    for (int p = 0; p < 4; ++p) {
      const int j0 = (4 - 2 * p) > 0 ? (4 - 2 * p) : 0;
      const int j1 = (10 - 2 * p) < 7 ? (10 - 2 * p) : 7;
#pragma unroll
      for (int j = j0; j <= j1; ++j) {
        f32x2 a = {ra[j], ra[j]};
        f32x2 b = {rb[j + 2 * p - 4], rb[j + 2 * p - 3]};
        acc2[p] = __builtin_elementwise_fma(a, b, acc2[p]);
      }
    }
    acc2[0].y = fmaf(ra[3], rb[0], acc2[0].y);  // ox=1, j=3
    acc2[1].y = fmaf(ra[1], rb[0], acc2[1].y);  // ox=3, j=1
    acc2[2].x = fmaf(ra[7], rb[7], acc2[2].x);  // ox=4, j=7
    acc2[3].x = fmaf(ra[5], rb[7], acc2[3].x);  // ox=6, j=5
    if (WE) {
      f32x2 b0 = {rb[4], rb[5]}, a0 = {ra[0], ra[1]};
      f32x2 b1 = {rb[6], rb[7]}, a1 = {ra[2], ra[3]};
      e2 = __builtin_elementwise_fma(b0, a0, e2);
      e2 = __builtin_elementwise_fma(b1, a1, e2);
    }
  }
  if (WE) e = e2.x + e2.y;
}

// dy = 0 task: acc2[0]={acc[0],acc[1]}, acc2[1]={acc[2],acc[3]}, a4=acc[4].
__device__ __forceinline__ void corr_task0_pk(const float* src, f32x2 acc2[2], float& a4) {
  float R[8][8];
#pragma unroll
  for (int i = 0; i < 8; ++i) loadrow(src + i * 128, R[i]);

  f32x2 s2 = {0.f, 0.f};
#pragma unroll
  for (int i = 0; i < 8; ++i) {
    const float(&r)[8] = R[i];
#pragma unroll
    for (int j = 4; j <= 7; ++j) {
      f32x2 a = {r[j], r[j]};
      f32x2 b = {r[j - 4], r[j - 3]};
      acc2[0] = __builtin_elementwise_fma(a, b, acc2[0]);
    }
    acc2[0].y = fmaf(r[3], r[0], acc2[0].y);
#pragma unroll
    for (int j = 2; j <= 7; ++j) {
      f32x2 a = {r[j], r[j]};
      f32x2 b = {r[j - 2], r[j - 1]};
      acc2[1] = __builtin_elementwise_fma(a, b, acc2[1]);
    }
    acc2[1].y = fmaf(r[1], r[0], acc2[1].y);
#pragma unroll
    for (int j = 0; j < 8; j += 2) {
      f32x2 v = {r[j], r[j + 1]};
      s2 = __builtin_elementwise_fma(v, v, s2);
    }
  }
  a4 = s2.x + s2.y;
}

__global__ __launch_bounds__(1024) void lacorr2d_kernel(
    const float* __restrict__ x, float* __restrict__ out) {
  __shared__ __align__(16) float lds[8][31][64];  // 63.5 KB

  const int wave = threadIdx.x >> 6;   // 0..15
  const int g    = wave >> 2;          // tile-group 0..3
  const int r    = wave & 3;           // role within group
  const int lane = threadIdx.x & 63;
  const int w    = lane & 31;          // window col (31 = dead lane)
  const int hh   = lane >> 5;          // 0/1 within window-row pair

  const int q  = blockIdx.x & 3;       // hp quad
  const int bc = blockIdx.x >> 2;      // 0..511
  const int hp = q * 4 + g;            // window-row pair 0..15
  const int h  = hp * 2 + hh;          // 0..31 (31 invalid)
  const bool valid = (w < NW) && (h < NH);
  const int hc = valid ? h : 0;
  const int wc = valid ? w : 0;

  const float* src = x + (size_t)bc * (128 * 128) + (size_t)(hc * 4) * 128 + wc * 4;
  float* wbase = &lds[2 * g + hh][wc][0];
  const int sw = wc & 7;  // swizzle key

  f32x2 acc2[4] = {{0.f, 0.f}, {0.f, 0.f}, {0.f, 0.f}, {0.f, 0.f}};
  float e = 0.f;

#define LDS_ST(e4, a, b, c, d)                                              \
  do {                                                                      \
    f32x4 v_ = {a, b, c, d};                                                \
    *reinterpret_cast<f32x4*>(wbase + (((e4) ^ sw) << 2)) = v_;             \
  } while (0)

  if (r == 0) {                        // D4 (row 0) + D0 (row 4)
    corr_task_pk<4, false>(src, acc2, e);
    if (valid) {
      LDS_ST(0, acc2[0].x, acc2[0].y, acc2[1].x, acc2[1].y);
      LDS_ST(1, acc2[2].x, acc2[2].y, acc2[3].x, acc2[3].y);
    }
    f32x2 b2[2] = {{0.f, 0.f}, {0.f, 0.f}};
    float a4 = 0.f;
    corr_task0_pk(src, b2, a4);
    if (valid) {
      LDS_ST(8, b2[0].x, b2[0].y, b2[1].x, b2[1].y);
      LDS_ST(9, a4,      b2[1].y, b2[1].x, b2[0].y);
    }
  } else if (r == 1) {                 // D1: rows 3 & 5
    corr_task_pk<1, true>(src, acc2, e);
    if (valid) {
      LDS_ST(6,  acc2[0].x, acc2[0].y, acc2[1].x, acc2[1].y);
      LDS_ST(7,  acc2[2].x, acc2[2].y, acc2[3].x, acc2[3].y);
      LDS_ST(10, e,         acc2[3].y, acc2[3].x, acc2[2].y);
      LDS_ST(11, acc2[2].x, acc2[1].y, acc2[1].x, acc2[0].y);
    }
  } else if (r == 2) {                 // D2: rows 2 & 6
    corr_task_pk<2, true>(src, acc2, e);
    if (valid) {
      LDS_ST(4,  acc2[0].x, acc2[0].y, acc2[1].x, acc2[1].y);
      LDS_ST(5,  acc2[2].x, acc2[2].y, acc2[3].x, acc2[3].y);
      LDS_ST(12, e,         acc2[3].y, acc2[3].x, acc2[2].y);
      LDS_ST(13, acc2[2].x, acc2[1].y, acc2[1].x, acc2[0].y);
    }
  } else {                             // D3: rows 1 & 7
    corr_task_pk<3, true>(src, acc2, e);
    if (valid) {
      LDS_ST(2,  acc2[0].x, acc2[0].y, acc2[1].x, acc2[1].y);
      LDS_ST(3,  acc2[2].x, acc2[2].y, acc2[3].x, acc2[3].y);
      LDS_ST(14, e,         acc2[3].y, acc2[3].x, acc2[2].y);
      LDS_ST(15, acc2[2].x, acc2[1].y, acc2[1].x, acc2[0].y);
    }
  }
#undef LDS_ST

  __syncthreads();

  // Copy out the block's 8 window-rows (7 for q=3: row 31 doesn't exist)
  // as ONE contiguous run: nrows*31*256 B, full lines, lane-consecutive.
  const int nrows = (q == 3) ? 7 : 8;
  float* orun = out + (size_t)(bc * NH + q * 8) * (NW * 64);
  const int total = nrows * NW * 16;  // float4 count
  for (int idx = threadIdx.x; idx < total; idx += 1024) {
    const int f4 = idx >> 4;
    const int hr = f4 / NW;
    const int ww = f4 % NW;
    const int e4 = idx & 15;
    f32x4 v = *reinterpret_cast<const f32x4*>(&lds[hr][ww][(e4 ^ (ww & 7)) << 2]);
    *reinterpret_cast<f32x4*>(orun + (size_t)idx * 4) = v;
  }
}

extern "C" void kernel_launch(void* const* d_in, const int* in_sizes, int n_in,
                              void* d_out, int out_size, void* d_ws, size_t ws_size,
                              hipStream_t stream) {
  const float* x = (const float*)d_in[0];
  float* out = (float*)d_out;
  // 512 bc-planes x 4 hp-quads
  lacorr2d_kernel<<<512 * 4, 1024, 0, stream>>>(x, out);
}